// Round 5
// baseline (83.382 us; speedup 1.0000x reference)
//
#include <hip/hip_runtime.h>
#include <hip/hip_bf16.h>
#include <math.h>

// Fused attention-gate, round 5: weights-in-registers + conflict-free swizzle.
//   g = BN(in_g @ Wg); x = BN(in_x @ Wx); s = relu(g+x)
//   psi = sigmoid(BN(s @ Wp)); out = x * psi
// C'[f][px] = W^T . pix^T. W held in VGPRs (full K=256, both tensors).
// Pixels staged to LDS as the MFMA B-operand, 16-px tiles, double-buffered,
// 8 tiles/block, ONE barrier per tile. LDS swizzle XORs row into 16B-slot
// bits 2-4 (byte bits 6-8) so slot low bits (=l4) are untouched -> 2-way max.

typedef __bf16 bf16x8 __attribute__((ext_vector_type(8)));
typedef float f32x4 __attribute__((ext_vector_type(4)));

__device__ __forceinline__ unsigned short f2bf(float f) {
  union { float f; unsigned u; } v; v.f = f;
  unsigned r = (v.u + 0x7fffu + ((v.u >> 16) & 1u)) >> 16;
  return (unsigned short)r;
}

__device__ __forceinline__ bf16x8 cvt8(float4 a, float4 b) {
  bf16x8 r;
  r[0]=(__bf16)a.x; r[1]=(__bf16)a.y; r[2]=(__bf16)a.z; r[3]=(__bf16)a.w;
  r[4]=(__bf16)b.x; r[5]=(__bf16)b.y; r[6]=(__bf16)b.z; r[7]=(__bf16)b.w;
  return r;
}

// ---------------- pre-kernel: fold BN into weights, fragment-linear ----------------
// Wfrag layout: [ftile(8)][ksg(8)][lane(64)][slot(8)] bf16 (64KB per tensor)
// lane l of fragment (ftile,ksg) holds W'[f=ftile*16+(l&15)][k=ksg*32+(l>>4)*8+slot]
__global__ __launch_bounds__(256) void fold_weights(
    const float* __restrict__ Wg, const float* __restrict__ bg,
    const float* __restrict__ gg, const float* __restrict__ beg,
    const float* __restrict__ mg, const float* __restrict__ vg,
    const float* __restrict__ Wx, const float* __restrict__ bx,
    const float* __restrict__ gx, const float* __restrict__ bex,
    const float* __restrict__ mx, const float* __restrict__ vx,
    const float* __restrict__ Wp, const float* __restrict__ bp,
    const float* __restrict__ gp, const float* __restrict__ bep,
    const float* __restrict__ mp, const float* __restrict__ vp,
    unsigned short* __restrict__ Bfg, unsigned short* __restrict__ Bfx,
    float* __restrict__ cg, float* __restrict__ cx,
    float* __restrict__ wps, float* __restrict__ cps) {
  int idx = blockIdx.x * 256 + threadIdx.x;  // 0..32767 = 256(c) * 128(f)
  int c = idx >> 7;    // Cin / k index
  int f = idx & 127;   // F index
  float ivg = gg[f] * rsqrtf(vg[f] + 1e-3f);
  float ivx = gx[f] * rsqrtf(vx[f] + 1e-3f);
  int ftile = f >> 4;
  int ksg = c >> 5;
  int lane = (((c >> 3) & 3) << 4) | (f & 15);
  int slot = c & 7;
  int off = ((ftile * 8 + ksg) * 64 + lane) * 8 + slot;
  Bfg[off] = f2bf(Wg[c * 128 + f] * ivg);
  Bfx[off] = f2bf(Wx[c * 128 + f] * ivx);
  if (idx < 128) {
    float ivg2 = gg[idx] * rsqrtf(vg[idx] + 1e-3f);
    float ivx2 = gx[idx] * rsqrtf(vx[idx] + 1e-3f);
    cg[idx] = bg[idx] * ivg2 + beg[idx] - mg[idx] * ivg2;
    cx[idx] = bx[idx] * ivx2 + bex[idx] - mx[idx] * ivx2;
    float ip = gp[0] * rsqrtf(vp[0] + 1e-3f);
    wps[idx] = Wp[idx] * ip;
    if (idx == 0) cps[0] = bp[0] * ip + bep[0] - mp[0] * ip;
  }
}

// ---------------- main fused kernel ----------------
// 512 threads = 8 waves; wave wid owns f-tile wid (16 f), W in registers.
// Each block: 8 consecutive 16-pixel tiles, 1 barrier per tile.
__global__ __launch_bounds__(512, 4) void attn_gate_main(
    const float* __restrict__ ing, const float* __restrict__ inx,
    const unsigned short* __restrict__ Wfg, const unsigned short* __restrict__ Wfx,
    const float* __restrict__ cgp, const float* __restrict__ cxp,
    const float* __restrict__ wpp, const float* __restrict__ cpp,
    float* __restrict__ out) {
  __shared__ __align__(16) short pixT[2][2][4096];   // [buf][tensor][16px*256k] 32KB
  __shared__ __align__(16) float xT[2][2048];         // [plane][16px*128f]      16KB
  __shared__ __align__(16) float psum[2][16][8];      //                          1KB

  const int tid = threadIdx.x;
  const int lane = tid & 63;
  const int wid = tid >> 6;        // f-tile of this wave
  const int l15 = lane & 15, l4 = lane >> 4;

  // ---- W fragments into registers (L2/L3-hot table) ----
  bf16x8 wfg[8], wfx[8];
  #pragma unroll
  for (int ksg = 0; ksg < 8; ++ksg) {
    const int off = ((wid * 8 + ksg) * 64 + lane) * 8;
    wfg[ksg] = *reinterpret_cast<const bf16x8*>(Wfg + off);
    wfx[ksg] = *reinterpret_cast<const bf16x8*>(Wfx + off);
  }
  const int fb = wid * 16 + l4 * 4;  // this lane's 4 consecutive f = fb+reg
  const f32x4 cgv = *reinterpret_cast<const f32x4*>(cgp + fb);
  const f32x4 cxv = *reinterpret_cast<const f32x4*>(cxp + fb);
  const f32x4 wpv = *reinterpret_cast<const f32x4*>(wpp + fb);
  const float cpsv = cpp[0];

  // staging geometry: thread covers (px = tid>>5, 16B-slot sk = tid&31)
  const int spx = tid >> 5;
  const int sk = tid & 31;
  const int swoff = (spx << 9) | ((sk ^ ((spx & 7) << 2)) << 4);  // byte in 8KB plane
  const long tile0 = (long)blockIdx.x * 8;
  const float* gsrc = ing + (tile0 * 16 + spx) * 256 + sk * 8;
  const float* xsrc = inx + (tile0 * 16 + spx) * 256 + sk * 8;

  // ---- prologue: stage tile 0 ----
  {
    float4 a0 = *reinterpret_cast<const float4*>(gsrc);
    float4 a1 = *reinterpret_cast<const float4*>(gsrc + 4);
    float4 b0 = *reinterpret_cast<const float4*>(xsrc);
    float4 b1 = *reinterpret_cast<const float4*>(xsrc + 4);
    *reinterpret_cast<bf16x8*>((char*)&pixT[0][0][0] + swoff) = cvt8(a0, a1);
    *reinterpret_cast<bf16x8*>((char*)&pixT[0][1][0] + swoff) = cvt8(b0, b1);
  }
  __syncthreads();

  #pragma unroll 2
  for (int t = 0; t < 8; ++t) {
    const int buf = t & 1;
    // issue next tile's global loads early (hidden under this tile's compute)
    float4 sg0, sg1, sx0, sx1;
    if (t < 7) {
      const float* g_ = gsrc + (t + 1) * 4096;
      const float* x_ = xsrc + (t + 1) * 4096;
      sg0 = *reinterpret_cast<const float4*>(g_);
      sg1 = *reinterpret_cast<const float4*>(g_ + 4);
      sx0 = *reinterpret_cast<const float4*>(x_);
      sx1 = *reinterpret_cast<const float4*>(x_ + 4);
    }

    // ---- compute: 16 ds_read + 16 MFMA, zero global loads ----
    f32x4 accg = {0.f, 0.f, 0.f, 0.f}, accx = {0.f, 0.f, 0.f, 0.f};
    #pragma unroll
    for (int ksg = 0; ksg < 8; ++ksg) {
      const int ra = (l15 << 9) | ((((ksg << 2) | l4) ^ ((l15 & 7) << 2)) << 4);
      bf16x8 pg = *reinterpret_cast<const bf16x8*>((const char*)&pixT[buf][0][0] + ra);
      bf16x8 px = *reinterpret_cast<const bf16x8*>((const char*)&pixT[buf][1][0] + ra);
      accg = __builtin_amdgcn_mfma_f32_16x16x32_bf16(wfg[ksg], pg, accg, 0, 0, 0);
      accx = __builtin_amdgcn_mfma_f32_16x16x32_bf16(wfx[ksg], px, accx, 0, 0, 0);
    }

    // ---- epilogue: bias, relu(g+x), psi partials, x-tile transpose ----
    // C/D layout: px = lane&15, f = fb + reg
    f32x4 xv;
    float part = 0.f;
    #pragma unroll
    for (int reg = 0; reg < 4; ++reg) {
      float gv = accg[reg] + cgv[reg];
      xv[reg] = accx[reg] + cxv[reg];
      float s = gv + xv[reg];
      s = s > 0.f ? s : 0.f;
      part += s * wpv[reg];
    }
    part += __shfl_xor(part, 16);   // sum over the 4 l4-groups (16 f of wave)
    part += __shfl_xor(part, 32);
    if (lane < 16) psum[buf][lane][wid] = part;
    const int xoff = (l15 << 9) | ((((wid << 2) | l4) ^ ((l15 & 7) << 2)) << 4);
    *reinterpret_cast<f32x4*>((char*)&xT[buf][0] + xoff) = xv;

    // ---- write next tile's staged data (disjoint buffer; pre-barrier) ----
    if (t < 7) {
      *reinterpret_cast<bf16x8*>((char*)&pixT[buf ^ 1][0][0] + swoff) = cvt8(sg0, sg1);
      *reinterpret_cast<bf16x8*>((char*)&pixT[buf ^ 1][1][0] + swoff) = cvt8(sx0, sx1);
    }
    __syncthreads();

    // ---- store: psi (redundant per-px sigmoid), coalesced float4 out ----
    {
      const f32x4 pa = *reinterpret_cast<const f32x4*>(&psum[buf][spx][0]);
      const f32x4 pb = *reinterpret_cast<const f32x4*>(&psum[buf][spx][4]);
      const float z = pa[0] + pa[1] + pa[2] + pa[3]
                    + pb[0] + pb[1] + pb[2] + pb[3] + cpsv;
      const float psi = 1.f / (1.f + __expf(-z));
      f32x4 xr = *reinterpret_cast<const f32x4*>((const char*)&xT[buf][0] + swoff);
      xr[0] *= psi; xr[1] *= psi; xr[2] *= psi; xr[3] *= psi;
      *reinterpret_cast<f32x4*>(out + ((tile0 + t) * 16 + spx) * 128 + sk * 4) = xr;
    }
  }
}

extern "C" void kernel_launch(void* const* d_in, const int* in_sizes, int n_in,
                              void* d_out, int out_size, void* d_ws, size_t ws_size,
                              hipStream_t stream) {
  const float* ing = (const float*)d_in[0];
  const float* inx = (const float*)d_in[1];
  char* ws = (char*)d_ws;
  unsigned short* Bfg = (unsigned short*)ws;                 // 64 KB
  unsigned short* Bfx = (unsigned short*)(ws + 65536);       // 64 KB
  float* cg  = (float*)(ws + 131072);                        // 512 B
  float* cx  = (float*)(ws + 131584);                        // 512 B
  float* wps = (float*)(ws + 132096);                        // 512 B
  float* cps = (float*)(ws + 132608);                        // 4 B

  fold_weights<<<128, 256, 0, stream>>>(
      (const float*)d_in[2],  (const float*)d_in[3],  (const float*)d_in[4],
      (const float*)d_in[5],  (const float*)d_in[6],  (const float*)d_in[7],
      (const float*)d_in[8],  (const float*)d_in[9],  (const float*)d_in[10],
      (const float*)d_in[11], (const float*)d_in[12], (const float*)d_in[13],
      (const float*)d_in[14], (const float*)d_in[15], (const float*)d_in[16],
      (const float*)d_in[17], (const float*)d_in[18], (const float*)d_in[19],
      Bfg, Bfx, cg, cx, wps, cps);

  const int npix = in_sizes[0] / 256;   // 131072
  const int ntiles = npix / 16;         // 8192
  attn_gate_main<<<ntiles / 8, 512, 0, stream>>>(
      ing, inx, Bfg, Bfx, cg, cx, wps, cps, (float*)d_out);
}